// Round 7
// baseline (1095.615 us; speedup 1.0000x reference)
//
#include <hip/hip_runtime.h>
#include <hip/hip_cooperative_groups.h>
#include <stdint.h>

namespace cg = cooperative_groups;

#define NN 1327104              // 9*384*384
#define NQ 331776               // NN/4 (uint4 elements)
#define GRID1 1024              // co-resident grid for full-array passes
#define NT1 (GRID1*256)
#define PRE_NMS_ 6000
#define POST_NMS_ 300
#define LB_CAP 4096
#define NPAD 6144               // 6000 padded to 96*64
#define NWORD 96                // NPAD/64
#define KB 16                   // batch size for seq rounds

// ---------- helpers ----------

static __device__ __forceinline__ uint32_t score_key(float s) {
  uint32_t b = __float_as_uint(s);
  uint32_t u = b ^ (((int32_t)b < 0) ? 0xFFFFFFFFu : 0x80000000u);
  return ~u;                     // ascending key == descending score
}

static __device__ __forceinline__ uint32_t f2s(float v) {
  uint32_t b = __float_as_uint(v);
  return b ^ (((int32_t)b < 0) ? 0xFFFFFFFFu : 0x80000000u);
}

// Exact replication of reference box decode + _clip_boxes + keep mask.
static __device__ __forceinline__ void compute_box(float4 an, float4 de,
    float& x1, float& y1, float& wc, float& hc, bool& keep) {
  float bx = fmaxf(an.x + de.x, 0.0f);
  float by = fmaxf(an.y + de.y, 0.0f);
  float bw = fmaxf(an.z + de.z, 0.0f);
  float bh = fmaxf(an.w + de.w, 0.0f);
  float x2 = bx + bw - 1.0f;
  float y2 = by + bh - 1.0f;
  x1 = fminf(bx, 383.0f);
  y1 = fminf(by, 383.0f);
  x2 = fminf(x2, 383.0f);
  y2 = fminf(y2, 383.0f);
  wc = x2 - x1 + 1.0f;
  hc = y2 - y1 + 1.0f;
  keep = (wc >= 2.0f) && (hc >= 2.0f);
}

// ---------- phase bodies (shared by fused + fallback kernels) ----------

static __device__ __forceinline__ void phaseA_body(const float* __restrict__ scores,
    const float4* __restrict__ deltas, const float4* __restrict__ anchors,
    uint32_t* __restrict__ darr, uint32_t* __restrict__ hist) {
  __shared__ uint32_t lh[256];
  int t = threadIdx.x;
  lh[t] = 0;
  __syncthreads();
  int gid = blockIdx.x * 256 + t;
  for (int i = gid; i < NN; i += NT1) {
    float x1, y1, wc, hc; bool keep;
    compute_box(anchors[i], deltas[i], x1, y1, wc, hc, keep);
    uint32_t d = keep ? score_key(scores[i]) : 0xFF800000u;   // key(-inf)
    darr[i] = d;
    atomicAdd(&lh[d >> 24], 1u);
  }
  __syncthreads();
  uint32_t c = lh[t];
  if (c) atomicAdd(&hist[t], c);
}

static __device__ __forceinline__ void phaseBC_body(const uint4* __restrict__ dv,
    const uint32_t* __restrict__ ctr, uint32_t* __restrict__ hist, int level) {
  __shared__ uint32_t lh[256];
  int t = threadIdx.x;
  lh[t] = 0;
  __syncthreads();
  uint32_t match, shift;
  if (level == 2) { match = ctr[4]; shift = 24; }
  else            { match = (ctr[4] << 8) | ctr[5]; shift = 16; }
  int gid = blockIdx.x * 256 + t;
  for (int g = gid; g < NQ; g += NT1) {
    uint4 v = dv[g];
    uint32_t arr[4] = {v.x, v.y, v.z, v.w};
    #pragma unroll
    for (int k = 0; k < 4; ++k) {
      uint32_t d = arr[k];
      if ((d >> shift) == match) atomicAdd(&lh[(d >> (shift - 8)) & 255u], 1u);
    }
  }
  __syncthreads();
  uint32_t c = lh[t];
  if (c) atomicAdd(&hist[t], c);
}

// caller guarantees threadIdx.x < 64 (one wave)
static __device__ __forceinline__ void pick8_body(uint32_t* __restrict__ hist,
                                                  uint32_t* __restrict__ ctr, int slot) {
  int l = threadIdx.x;
  uint32_t base = ctr[3];
  uint32_t h0 = hist[l*4], h1 = hist[l*4+1], h2 = hist[l*4+2], h3 = hist[l*4+3];
  hist[l*4] = 0; hist[l*4+1] = 0; hist[l*4+2] = 0; hist[l*4+3] = 0;
  uint32_t c0 = h0, c1 = c0 + h1, c2 = c1 + h2, c3 = c2 + h3;
  uint32_t p = c3;
  #pragma unroll
  for (int off = 1; off < 64; off <<= 1) {
    uint32_t u = __shfl_up(p, off);
    if (l >= off) p += u;
  }
  uint32_t excl = p - c3;
  bool hit = (base + p >= PRE_NMS_) && (base + excl < PRE_NMS_);
  if (hit) {                                // exactly one lane
    uint32_t k, cb;
    if      (base + excl + c0 >= PRE_NMS_) { k = 0; cb = 0;  }
    else if (base + excl + c1 >= PRE_NMS_) { k = 1; cb = c0; }
    else if (base + excl + c2 >= PRE_NMS_) { k = 2; cb = c1; }
    else                                   { k = 3; cb = c2; }
    ctr[slot] = (uint32_t)(l * 4) + k;
    ctr[3] = base + excl + cb;
  }
}

static __device__ __forceinline__ void gather_body(const uint4* __restrict__ dv,
    uint32_t* __restrict__ ctr, uint64_t* __restrict__ L, uint64_t* __restrict__ Lb) {
  int gid = blockIdx.x * 256 + threadIdx.x;
  uint32_t P24 = (ctr[4] << 16) | (ctr[5] << 8) | ctr[6];
  for (int g = gid; g < NQ; g += NT1) {
    uint4 v = dv[g];
    uint32_t arr[4] = {v.x, v.y, v.z, v.w};
    #pragma unroll
    for (int k = 0; k < 4; ++k) {
      uint32_t d = arr[k];
      uint32_t p24 = d >> 8;
      uint32_t idx = (uint32_t)(g * 4 + k);
      if (p24 < P24) {
        uint32_t p = atomicAdd(&ctr[0], 1u);
        if (p < PRE_NMS_) L[p] = ((uint64_t)d << 32) | idx;
      } else if (p24 == P24) {
        uint32_t p = atomicAdd(&ctr[1], 1u);
        if (p < LB_CAP) Lb[p] = ((uint64_t)d << 32) | idx;
      }
    }
  }
}

// parallel boundary rank-select: one thread per boundary item, global (L2-hot) reads
static __device__ __forceinline__ void rankb_body(const uint32_t* __restrict__ ctr,
    const uint64_t* __restrict__ Lb, uint64_t* __restrict__ L) {
  uint32_t Cb = ctr[1]; if (Cb > LB_CAP) Cb = LB_CAP;
  uint32_t C0 = ctr[3];
  uint32_t T = PRE_NMS_ - C0;
  uint32_t gid = blockIdx.x * blockDim.x + threadIdx.x;
  if (gid < Cb) {
    uint64_t k = Lb[gid];
    uint32_t r = 0;
    for (uint32_t j = 0; j < Cb; ++j) r += (Lb[j] < k) ? 1u : 0u;
    if (r < T) L[C0 + r] = k;
  }
}

static __device__ __forceinline__ void prep_body(const uint64_t* __restrict__ L,
    const float4* __restrict__ deltas, const float4* __restrict__ anchors,
    uint64_t* __restrict__ keyhi, uint32_t* __restrict__ keylo,
    float4* __restrict__ box4u) {
  int i = blockIdx.x * blockDim.x + threadIdx.x;
  if (i >= NPAD) return;
  if (i < PRE_NMS_) {
    uint64_t key = L[i];
    uint32_t d = (uint32_t)(key >> 32), idx = (uint32_t)key;
    float x1, y1, wc, hc; bool keep;
    compute_box(anchors[idx], deltas[idx], x1, y1, wc, hc, keep);
    float y2 = y1 + hc - 1.0f;                 // exactly as reference _nms
    keyhi[i] = ((uint64_t)f2s(y2) << 32) | (uint32_t)(~d);
    keylo[i] = ~idx;
    box4u[i] = make_float4(x1, y1, wc, hc);
  } else {
    keyhi[i] = 0;
    keylo[i] = (uint32_t)(NPAD - i);           // unique sentinel tie-break
    box4u[i] = make_float4(0.f, 0.f, 0.f, 0.f);
  }
}

// pairwise rank, 512-thread blocks, 192 blocks: (i, chunk c, half h)
static __device__ __forceinline__ void rank_body(const uint64_t* __restrict__ keyhi,
    const uint32_t* __restrict__ keylo, uint32_t* __restrict__ rank2d) {
  __shared__ uint64_t shi[768];
  __shared__ uint32_t slo[768];
  int t = threadIdx.x;
  int ib = blockIdx.x >> 3, c = blockIdx.x & 7, base = c * 768;
  for (int j = t; j < 768; j += 512) { shi[j] = keyhi[base + j]; slo[j] = keylo[base + j]; }
  __syncthreads();
  int i = ib * 256 + (t >> 1);
  int h = t & 1;
  uint64_t hi = keyhi[i]; uint32_t lo = keylo[i];
  uint32_t cnt = 0;
  int j0 = h * 384;
  for (int j = j0; j < j0 + 384; ++j) {
    uint64_t hj = shi[j]; uint32_t lj = slo[j];
    cnt += ((hj > hi) || (hj == hi && lj > lo)) ? 1u : 0u;
  }
  rank2d[i * 16 + c * 2 + h] = cnt;
}

// fused scatter+mat: each block builds sorted boxes in ITS LDS, then IoU matrix
static __device__ __forceinline__ void matsc_body(const uint64_t* __restrict__ keyhi,
    const uint32_t* __restrict__ rank2d, const float4* __restrict__ box4u,
    float4* __restrict__ sobox, unsigned long long* __restrict__ valid,
    uint64_t* __restrict__ M) {
  __shared__ float4 sb[NPAD];       // 98,304 B
  __shared__ float  sa[NPAD];       // 24,576 B
  int t = threadIdx.x;
  int b = blockIdx.x;
  for (int i = t; i < NPAD; i += 512) {
    const uint4* rp = (const uint4*)(rank2d + (size_t)i * 16);
    uint4 r0 = rp[0], r1 = rp[1], r2 = rp[2], r3 = rp[3];
    uint32_t r = r0.x+r0.y+r0.z+r0.w + r1.x+r1.y+r1.z+r1.w
               + r2.x+r2.y+r2.z+r2.w + r3.x+r3.y+r3.z+r3.w;
    float4 bx = box4u[i];
    float x2 = bx.x + bx.z - 1.0f;              // exactly as reference _nms
    float y2 = bx.y + bx.w - 1.0f;
    sb[r] = make_float4(bx.x, bx.y, x2, y2);
    sa[r] = bx.z * bx.w;
    if (b == 0) {
      sobox[r] = bx;
      uint32_t d = ~(uint32_t)(keyhi[i] & 0xFFFFFFFFu);
      if (d < 0xFF800000u)                      // finite masked score only
        atomicOr(&valid[r >> 6], 1ull << (r & 63));
    }
  }
  __syncthreads();
  int wid = t >> 6, l = t & 63;
  #pragma unroll
  for (int rr = 0; rr < 4; ++rr) {
    int r = b * 32 + wid * 4 + rr;
    float4 rb = sb[r];
    for (int w = 0; w < NWORD; ++w) {
      int j = w * 64 + l;
      float4 cb = sb[j];
      float ca = sa[j];
      float xx1 = fmaxf(cb.x, rb.x), yy1 = fmaxf(cb.y, rb.y);
      float xx2 = fminf(cb.z, rb.z), yy2 = fminf(cb.w, rb.w);
      float iw = fmaxf(xx2 - xx1 + 1.0f, 0.0f);
      float ih = fmaxf(yy2 - yy1 + 1.0f, 0.0f);
      float ratio = (iw * ih) / ca;             // IEEE divide, exact semantics
      unsigned long long m = __ballot(!(ratio < 0.7f));
      if (l == 0) M[(size_t)r * NWORD + w] = m;
    }
  }
}

// batched-greedy sequential NMS — single wave, barrier-free (same-wave LDS is in-order)
#define FOR16(F) F(0) F(1) F(2) F(3) F(4) F(5) F(6) F(7) \
                 F(8) F(9) F(10) F(11) F(12) F(13) F(14) F(15)

static __device__ __forceinline__ void seq_body(const unsigned long long* __restrict__ valid,
    const uint64_t* __restrict__ M, const float4* __restrict__ sobox,
    float* __restrict__ out) {
  __shared__ int cslot[KB];
  int l = threadIdx.x;                          // < 64 (caller-guaranteed)
  unsigned long long v0 = valid[l];
  unsigned long long v1 = (l < 32) ? valid[64 + l] : 0ull;
  uint32_t cnt = 0;

  for (;;) {
    uint32_t n0 = (uint32_t)__popcll(v0);
    uint32_t inc0 = n0;
    #pragma unroll
    for (int off = 1; off < 64; off <<= 1) {
      uint32_t u = __shfl_up(inc0, off);
      if (l >= off) inc0 += u;
    }
    uint32_t T0 = __shfl(inc0, 63);
    uint32_t ex0 = inc0 - n0;
    uint32_t n1 = (uint32_t)__popcll(v1);
    uint32_t inc1 = n1;
    #pragma unroll
    for (int off = 1; off < 64; off <<= 1) {
      uint32_t u = __shfl_up(inc1, off);
      if (l >= off) inc1 += u;
    }
    uint32_t T1 = __shfl(inc1, 63);
    uint32_t ex1 = T0 + inc1 - n1;
    uint32_t TV = T0 + T1;
    if (cnt >= POST_NMS_ || TV == 0) break;
    uint32_t m = (TV < KB) ? TV : KB;

    if (l < KB) cslot[l] = 0;
    __builtin_amdgcn_sched_barrier(0);
    if (ex0 < KB) {
      unsigned long long w = v0; uint32_t r = ex0;
      while (w && r < KB) { int b = __ffsll(w) - 1; cslot[r] = l * 64 + b; ++r; w &= w - 1; }
    }
    if (ex1 < KB && v1) {
      unsigned long long w = v1; uint32_t r = ex1;
      while (w && r < KB) { int b = __ffsll(w) - 1; cslot[r] = (64 + l) * 64 + b; ++r; w &= w - 1; }
    }
    __builtin_amdgcn_sched_barrier(0);

#define ROWDECL(k) uint64_t rm0_##k = 0, rm1_##k = 0;
    FOR16(ROWDECL)
#undef ROWDECL
#define ROWLOAD(k) if (k < (int)m) { const uint64_t* p = M + (size_t)cslot[k] * NWORD; \
                     rm0_##k = p[l]; rm1_##k = (l < 32) ? p[64 + l] : 0ull; }
    FOR16(ROWLOAD)
#undef ROWLOAD
    float4 obox = make_float4(0.f, 0.f, 0.f, 0.f);
    if (l < KB) obox = sobox[cslot[l]];

    uint32_t cj = (l < KB) ? (uint32_t)cslot[l] : 0u;
    uint32_t wj = cj >> 6, bj = cj & 63;
    int srcA = (int)(wj & 63), srcB = (int)(wj & 31);
    uint32_t srow[KB];
#define SROW(k) { uint64_t a = __shfl((unsigned long long)rm0_##k, srcA); \
                  uint64_t b = __shfl((unsigned long long)rm1_##k, srcB); \
                  uint64_t sel = (wj < 64) ? a : b; \
                  uint32_t bit = (l < KB && k < (int)m) ? (uint32_t)((sel >> bj) & 1) : 0u; \
                  srow[k] = (uint32_t)(__ballot(bit) & 0xFFFFull); }
    FOR16(SROW)
#undef SROW

    uint32_t cnt0 = cnt;
    uint32_t wm = 0, supp = 0;
    #pragma unroll
    for (int k = 0; k < KB; ++k) {
      if (k < (int)m && cnt < POST_NMS_ && !((supp >> k) & 1)) {
        wm |= 1u << k; ++cnt; supp |= srow[k];
      }
    }

    if (l < KB && ((wm >> l) & 1)) {
      uint32_t pos = cnt0 + (uint32_t)__popc(wm & ((1u << l) - 1));
      *(float4*)(out + (size_t)pos * 4) = obox;
    }

    uint64_t comb0 = 0, comb1 = 0;
#define COMB(k) if ((wm >> k) & 1) { comb0 |= rm0_##k; comb1 |= rm1_##k; }
    FOR16(COMB)
#undef COMB
    v0 &= ~comb0; v1 &= ~comb1;
  }

  for (int j = l; j < (int)(POST_NMS_ - cnt) * 4; j += 64) out[cnt * 4 + j] = 0.0f;
}

// ---------- fused cooperative kernels ----------

__global__ __launch_bounds__(256, 4) void k_front(
    const float* __restrict__ scores, const float4* __restrict__ deltas,
    const float4* __restrict__ anchors, uint32_t* __restrict__ darr,
    uint32_t* __restrict__ hist, uint32_t* __restrict__ ctr,
    uint64_t* __restrict__ L, uint64_t* __restrict__ Lb,
    uint64_t* __restrict__ keyhi, uint32_t* __restrict__ keylo,
    float4* __restrict__ box4u) {
  cg::grid_group grid = cg::this_grid();
  const uint4* dv = (const uint4*)darr;
  bool p0 = (blockIdx.x == 0) && (threadIdx.x < 64);

  phaseA_body(scores, deltas, anchors, darr, hist);
  grid.sync();
  if (p0) pick8_body(hist, ctr, 4);
  grid.sync();
  phaseBC_body(dv, ctr, hist, 2);
  grid.sync();
  if (p0) pick8_body(hist, ctr, 5);
  grid.sync();
  phaseBC_body(dv, ctr, hist, 3);
  grid.sync();
  if (p0) pick8_body(hist, ctr, 6);
  grid.sync();
  gather_body(dv, ctr, L, Lb);
  grid.sync();
  rankb_body(ctr, Lb, L);
  grid.sync();
  prep_body(L, deltas, anchors, keyhi, keylo, box4u);
}

__global__ __launch_bounds__(512) void k_back(
    const uint64_t* __restrict__ keyhi, const uint32_t* __restrict__ keylo,
    const float4* __restrict__ box4u, uint32_t* __restrict__ rank2d,
    float4* __restrict__ sobox, unsigned long long* __restrict__ valid,
    uint64_t* __restrict__ M, float* __restrict__ out) {
  cg::grid_group grid = cg::this_grid();
  rank_body(keyhi, keylo, rank2d);
  grid.sync();
  matsc_body(keyhi, rank2d, box4u, sobox, valid, M);
  grid.sync();
  if (blockIdx.x == 0 && threadIdx.x < 64) seq_body(valid, M, sobox, out);
}

// ---------- fallback (non-cooperative) wrappers ----------

__global__ __launch_bounds__(256) void k_hA(const float* scores, const float4* deltas,
    const float4* anchors, uint32_t* darr, uint32_t* hist) {
  phaseA_body(scores, deltas, anchors, darr, hist);
}
__global__ __launch_bounds__(256) void k_hBC(const uint4* dv, const uint32_t* ctr,
    uint32_t* hist, int level) {
  phaseBC_body(dv, ctr, hist, level);
}
__global__ __launch_bounds__(64) void k_pick8(uint32_t* hist, uint32_t* ctr, int slot) {
  pick8_body(hist, ctr, slot);
}
__global__ __launch_bounds__(256) void k_gather(const uint4* dv, uint32_t* ctr,
    uint64_t* L, uint64_t* Lb) {
  gather_body(dv, ctr, L, Lb);
}
__global__ __launch_bounds__(256) void k_rankb(const uint32_t* ctr, const uint64_t* Lb,
    uint64_t* L) {
  rankb_body(ctr, Lb, L);
}
__global__ __launch_bounds__(256) void k_prep(const uint64_t* L, const float4* deltas,
    const float4* anchors, uint64_t* keyhi, uint32_t* keylo, float4* box4u) {
  prep_body(L, deltas, anchors, keyhi, keylo, box4u);
}
__global__ __launch_bounds__(512) void k_rank(const uint64_t* keyhi, const uint32_t* keylo,
    uint32_t* rank2d) {
  rank_body(keyhi, keylo, rank2d);
}
__global__ __launch_bounds__(512) void k_matsc(const uint64_t* keyhi, const uint32_t* rank2d,
    const float4* box4u, float4* sobox, unsigned long long* valid, uint64_t* M) {
  matsc_body(keyhi, rank2d, box4u, sobox, valid, M);
}
__global__ __launch_bounds__(64) void k_seq(const unsigned long long* valid,
    const uint64_t* M, const float4* sobox, float* out) {
  seq_body(valid, M, sobox, out);
}

// ---------- launch ----------
extern "C" void kernel_launch(void* const* d_in, const int* in_sizes, int n_in,
                              void* d_out, int out_size, void* d_ws, size_t ws_size,
                              hipStream_t stream) {
  const float*  scores  = (const float*)d_in[0];
  const float4* deltas  = (const float4*)d_in[1];
  const float4* anchors = (const float4*)d_in[2];
  float* out = (float*)d_out;

  uint8_t* w8 = (uint8_t*)d_ws;
  // region 0: d[] (5,308,416 B), live k_front only; then overlaid by M + sobox
  uint32_t* darr  = (uint32_t*)w8;
  uint64_t* M     = (uint64_t*)w8;                          // 4,718,592
  float4*   sobox = (float4*)(w8 + 4841472);                //  98,304 -> 4,939,776
  // region 1 (fresh): @5,308,416
  uint64_t* keyhi  = (uint64_t*)(w8 + 5308416);             //  49,152
  uint32_t* keylo  = (uint32_t*)(w8 + 5357568);             //  24,576
  float4*   box4u  = (float4*)  (w8 + 5382144);             //  98,304
  uint32_t* rank2d = (uint32_t*)(w8 + 5480448);             // 393,216 -> 5,873,664
  // region 2: persistent small (hist+ctr+valid contiguous for single memset)
  uint32_t* hist = (uint32_t*)(w8 + 5873664);               //   1,024
  uint32_t* ctr  = (uint32_t*)(w8 + 5874688);               //      64
  unsigned long long* valid = (unsigned long long*)(w8 + 5874752); // 1,024
  uint64_t* L    = (uint64_t*)(w8 + 5875776);               //  48,000
  uint64_t* Lb   = (uint64_t*)(w8 + 5923776);               //  32,768 -> 5,956,544 total

  const uint4* dv = (const uint4*)darr;

  hipMemsetAsync(hist, 0, 2112, stream);     // hist + ctr + valid

  void* a1[] = {(void*)&scores, (void*)&deltas, (void*)&anchors, (void*)&darr,
                (void*)&hist, (void*)&ctr, (void*)&L, (void*)&Lb,
                (void*)&keyhi, (void*)&keylo, (void*)&box4u};
  hipError_t e1 = hipLaunchCooperativeKernel(reinterpret_cast<void*>(k_front),
                                             dim3(GRID1), dim3(256), a1, 0, stream);
  if (e1 == hipSuccess) {
    void* a2[] = {(void*)&keyhi, (void*)&keylo, (void*)&box4u, (void*)&rank2d,
                  (void*)&sobox, (void*)&valid, (void*)&M, (void*)&out};
    hipLaunchCooperativeKernel(reinterpret_cast<void*>(k_back),
                               dim3(192), dim3(512), a2, 0, stream);
  } else {
    // fallback: equivalent non-cooperative chain
    k_hA   <<<GRID1, 256, 0, stream>>>(scores, deltas, anchors, darr, hist);
    k_pick8<<<1, 64, 0, stream>>>(hist, ctr, 4);
    k_hBC  <<<GRID1, 256, 0, stream>>>(dv, ctr, hist, 2);
    k_pick8<<<1, 64, 0, stream>>>(hist, ctr, 5);
    k_hBC  <<<GRID1, 256, 0, stream>>>(dv, ctr, hist, 3);
    k_pick8<<<1, 64, 0, stream>>>(hist, ctr, 6);
    k_gather<<<GRID1, 256, 0, stream>>>(dv, ctr, L, Lb);
    k_rankb <<<16, 256, 0, stream>>>(ctr, Lb, L);
    k_prep  <<<NPAD / 256, 256, 0, stream>>>(L, deltas, anchors, keyhi, keylo, box4u);
    k_rank  <<<192, 512, 0, stream>>>(keyhi, keylo, rank2d);
    k_matsc <<<192, 512, 0, stream>>>(keyhi, rank2d, box4u, sobox, valid, M);
    k_seq   <<<1, 64, 0, stream>>>(valid, M, sobox, out);
  }
}

// Round 8
// 311.840 us; speedup vs baseline: 3.5134x; 3.5134x over previous
//
#include <hip/hip_runtime.h>
#include <stdint.h>

#define NN 1327104              // 9*384*384
#define NQ 331776               // NN/4 (uint4 elements)
#define NB 1296                 // NB*256 == NQ ; NB*256*4 == NN
#define PRE_NMS_ 6000
#define POST_NMS_ 300
#define LB_CAP 4096
#define NPAD 6144               // 6000 padded to 96*64
#define NWORD 96                // NPAD/64
#define KB 16                   // batch size for seq rounds
#define MATB 192                // matsc grid

// ---------- helpers ----------

static __device__ __forceinline__ uint32_t score_key(float s) {
  uint32_t b = __float_as_uint(s);
  uint32_t u = b ^ (((int32_t)b < 0) ? 0xFFFFFFFFu : 0x80000000u);
  return ~u;                     // ascending key == descending score
}

static __device__ __forceinline__ uint32_t f2s(float v) {
  uint32_t b = __float_as_uint(v);
  return b ^ (((int32_t)b < 0) ? 0xFFFFFFFFu : 0x80000000u);
}

// Exact replication of reference box decode + _clip_boxes + keep mask.
static __device__ __forceinline__ void compute_box(float4 an, float4 de,
    float& x1, float& y1, float& wc, float& hc, bool& keep) {
  float bx = fmaxf(an.x + de.x, 0.0f);
  float by = fmaxf(an.y + de.y, 0.0f);
  float bw = fmaxf(an.z + de.z, 0.0f);
  float bh = fmaxf(an.w + de.w, 0.0f);
  float x2 = bx + bw - 1.0f;
  float y2 = by + bh - 1.0f;
  x1 = fminf(bx, 383.0f);
  y1 = fminf(by, 383.0f);
  x2 = fminf(x2, 383.0f);
  y2 = fminf(y2, 383.0f);
  wc = x2 - x1 + 1.0f;
  hc = y2 - y1 + 1.0f;
  keep = (wc >= 2.0f) && (hc >= 2.0f);
}

// uniform 18-bit fixed-point bucket (x 2^18 is EXACT for floats -> monotone)
// reversed so ascending bucket == descending score
static __device__ __forceinline__ uint32_t kb18_of(float s) {
  return (uint32_t)(s * 262144.0f);          // 0..262143 for s in [0,1)
}

static __device__ __forceinline__ uint32_t wscan(uint32_t v, int l) {
  #pragma unroll
  for (int off = 1; off < 64; off <<= 1) {
    uint32_t u = __shfl_up(v, off);
    if (l >= off) v += u;
  }
  return v;
}

// ---------- pure pick level 1: hist1[320] (257 used), returns (selR8, base1) ----------
static __device__ __forceinline__ void pick1_f(const uint32_t* __restrict__ h1,
                                               uint32_t& selR8, uint32_t& base1) {
  int l = threadIdx.x & 63;
  uint32_t a0 = h1[l*5], a1 = h1[l*5+1], a2 = h1[l*5+2], a3 = h1[l*5+3], a4 = h1[l*5+4];
  uint32_t c0 = a0, c1 = c0+a1, c2 = c1+a2, c3 = c2+a3, c4 = c3+a4;
  uint32_t inc = wscan(c4, l);
  uint32_t excl = inc - c4;
  bool hit = (excl < PRE_NMS_) && (inc >= PRE_NMS_);
  unsigned long long hb = __ballot(hit);
  int hl = __ffsll(hb) - 1;
  uint32_t k, cb;
  if      (excl + c0 >= PRE_NMS_) { k = 0; cb = 0;  }
  else if (excl + c1 >= PRE_NMS_) { k = 1; cb = c0; }
  else if (excl + c2 >= PRE_NMS_) { k = 2; cb = c1; }
  else if (excl + c3 >= PRE_NMS_) { k = 3; cb = c2; }
  else                            { k = 4; cb = c3; }
  selR8 = __shfl(l*5u + k, hl);
  base1 = __shfl(excl + cb, hl);
}

// ---------- pure pick level 2: hist2[1024], returns (selR10, C0) ----------
static __device__ __forceinline__ void pick2_f(const uint32_t* __restrict__ h2,
                                               uint32_t base1,
                                               uint32_t& selR10, uint32_t& C0) {
  int l = threadIdx.x & 63;
  const uint4* p = (const uint4*)(h2 + l * 16);
  uint4 va = p[0], vb = p[1], vc = p[2], vd = p[3];
  uint32_t h[16] = {va.x,va.y,va.z,va.w, vb.x,vb.y,vb.z,vb.w,
                    vc.x,vc.y,vc.z,vc.w, vd.x,vd.y,vd.z,vd.w};
  uint32_t cum[16]; cum[0] = h[0];
  #pragma unroll
  for (int k = 1; k < 16; ++k) cum[k] = cum[k-1] + h[k];
  uint32_t inc = wscan(cum[15], l);
  uint32_t excl = base1 + inc - cum[15];
  bool hit = (excl < PRE_NMS_) && (base1 + inc >= PRE_NMS_);
  unsigned long long hb = __ballot(hit);
  int hl = __ffsll(hb) - 1;
  uint32_t k = 15, cb = cum[14];
  #pragma unroll
  for (int kk = 15; kk >= 0; --kk)
    if (excl + cum[kk] >= PRE_NMS_) { k = (uint32_t)kk; cb = kk ? cum[kk-1] : 0u; }
  selR10 = __shfl(l*16u + k, hl);
  C0 = __shfl(excl + cb, hl);
}

// ---------- K1: decode once, write d[], LDS hist over r8; zero hist2/ctr/valid ----------
__global__ __launch_bounds__(256) void k_hA(const float* __restrict__ scores,
                                            const float4* __restrict__ deltas,
                                            const float4* __restrict__ anchors,
                                            uint32_t* __restrict__ darr,
                                            uint32_t* __restrict__ hist1,
                                            uint32_t* __restrict__ zpad) {
  __shared__ uint32_t lh[320];
  int t = threadIdx.x;
  for (int j = t; j < 320; j += 256) lh[j] = 0;
  __syncthreads();
  int base = blockIdx.x * 256 + t;
  #pragma unroll
  for (int it = 0; it < 4; ++it) {
    int i = base + it * NQ;
    float x1, y1, wc, hc; bool keep;
    compute_box(anchors[i], deltas[i], x1, y1, wc, hc, keep);
    float s = scores[i];
    uint32_t d = keep ? score_key(s) : 0xFF800000u;   // key(-inf)
    darr[i] = d;
    uint32_t r8 = keep ? (255u - (kb18_of(s) >> 10)) : 256u;
    atomicAdd(&lh[r8], 1u);
  }
  __syncthreads();
  for (int j = t; j < 320; j += 256) {
    uint32_t c = lh[j];
    if (c) atomicAdd(&hist1[j], c);
  }
  // block 0 zeroes hist2[1024] + ctr[16] + valid[128] (nobody touches them in this kernel)
  if (blockIdx.x == 0) for (int j = t; j < 1024 + 16 + 128; j += 256) zpad[j] = 0;
}

// ---------- K2: refine 10 bits within selected r8 (reads only d[]) ----------
__global__ __launch_bounds__(256) void k_hB(const uint4* __restrict__ dv,
                                            const uint32_t* __restrict__ hist1,
                                            uint32_t* __restrict__ hist2) {
  __shared__ uint32_t lh2[1024];
  int t = threadIdx.x;
  uint32_t selR8, base1;
  pick1_f(hist1, selR8, base1);
  for (int j = t; j < 1024; j += 256) lh2[j] = 0;
  __syncthreads();
  uint4 v = dv[blockIdx.x * 256 + t];
  uint32_t arr[4] = {v.x, v.y, v.z, v.w};
  #pragma unroll
  for (int k = 0; k < 4; ++k) {
    uint32_t d = arr[k];
    if (d <= 0x7FFFFFFFu) {
      uint32_t kb = kb18_of(__uint_as_float(0x7FFFFFFFu - d));
      if ((255u - (kb >> 10)) == selR8) atomicAdd(&lh2[1023u - (kb & 1023u)], 1u);
    } else if (selR8 == 256u) {
      atomicAdd(&lh2[0], 1u);
    }
  }
  __syncthreads();
  for (int j = t; j < 1024; j += 256) {
    uint32_t c = lh2[j];
    if (c) atomicAdd(&hist2[j], c);
  }
}

// ---------- K3: gather candidates (above -> L, boundary -> Lb) ----------
__global__ __launch_bounds__(256) void k_gather(const uint4* __restrict__ dv,
                                                const uint32_t* __restrict__ hist1,
                                                const uint32_t* __restrict__ hist2,
                                                uint32_t* __restrict__ ctr,
                                                uint64_t* __restrict__ L,
                                                uint64_t* __restrict__ Lb) {
  __shared__ uint32_t s_sel8, s_sel10;
  int t = threadIdx.x;
  if (t < 64) {
    uint32_t sel8, base1, sel10, c0;
    pick1_f(hist1, sel8, base1);
    pick2_f(hist2, base1, sel10, c0);
    if (t == 0) { s_sel8 = sel8; s_sel10 = sel10; }
  }
  __syncthreads();
  uint32_t selR8 = s_sel8, selR10 = s_sel10;
  int g = blockIdx.x * 256 + t;
  uint4 v = dv[g];
  uint32_t arr[4] = {v.x, v.y, v.z, v.w};
  #pragma unroll
  for (int k = 0; k < 4; ++k) {
    uint32_t d = arr[k];
    uint32_t idx = (uint32_t)(g * 4 + k);
    bool above = false, boundary = false;
    if (d <= 0x7FFFFFFFu) {
      uint32_t kb = kb18_of(__uint_as_float(0x7FFFFFFFu - d));
      uint32_t r8 = 255u - (kb >> 10), r10 = 1023u - (kb & 1023u);
      above = (r8 < selR8) || (r8 == selR8 && r10 < selR10);
      boundary = (r8 == selR8) && (r10 == selR10);
    } else {
      boundary = (selR8 == 256u) && (selR10 == 0u);
    }
    if (above) {
      uint32_t p = atomicAdd(&ctr[0], 1u);
      if (p < PRE_NMS_) L[p] = ((uint64_t)d << 32) | idx;
    } else if (boundary) {
      uint32_t p = atomicAdd(&ctr[1], 1u);
      if (p < LB_CAP) Lb[p] = ((uint64_t)d << 32) | idx;
    }
  }
}

// ---------- K4: prep (+inline boundary rank-select) ----------
__global__ __launch_bounds__(256) void k_prep(const uint32_t* __restrict__ hist1,
                                              const uint32_t* __restrict__ hist2,
                                              const uint32_t* __restrict__ ctr,
                                              const uint64_t* __restrict__ L,
                                              const uint64_t* __restrict__ Lb,
                                              const float4* __restrict__ deltas,
                                              const float4* __restrict__ anchors,
                                              uint64_t* __restrict__ keyhi,
                                              uint32_t* __restrict__ keylo,
                                              float4* __restrict__ box4u) {
  uint32_t sel8, base1, sel10, C0;
  pick1_f(hist1, sel8, base1);
  pick2_f(hist2, base1, sel10, C0);
  int i = blockIdx.x * 256 + threadIdx.x;
  if (i >= NPAD) return;
  if (i < PRE_NMS_) {
    uint64_t mykey;
    if ((uint32_t)i < C0) {
      mykey = L[i];
    } else {
      uint32_t Cb = ctr[1]; if (Cb > LB_CAP) Cb = LB_CAP;
      uint32_t r = (uint32_t)i - C0;
      mykey = ~0ULL;
      for (uint32_t j = 0; j < Cb; ++j) {
        uint64_t kj = Lb[j];
        uint32_t rj = 0;
        for (uint32_t k = 0; k < Cb; ++k) rj += (Lb[k] < kj) ? 1u : 0u;
        if (rj == r) { mykey = kj; break; }
      }
    }
    uint32_t d = (uint32_t)(mykey >> 32), idx = (uint32_t)mykey;
    float x1, y1, wc, hc; bool keep;
    compute_box(anchors[idx], deltas[idx], x1, y1, wc, hc, keep);
    float y2 = y1 + hc - 1.0f;                 // exactly as reference _nms
    keyhi[i] = ((uint64_t)f2s(y2) << 32) | (uint32_t)(~d);
    keylo[i] = ~idx;
    box4u[i] = make_float4(x1, y1, wc, hc);
  } else {
    keyhi[i] = 0;
    keylo[i] = (uint32_t)(NPAD - i);           // unique sentinel tie-break
    box4u[i] = make_float4(0.f, 0.f, 0.f, 0.f);
  }
}

// ---------- K5: pairwise rank, chunked; plain stores rank2d[i][16] ----------
__global__ __launch_bounds__(512) void k_rank(const uint64_t* __restrict__ keyhi,
                                              const uint32_t* __restrict__ keylo,
                                              uint32_t* __restrict__ rank2d) {
  __shared__ uint64_t shi[768];
  __shared__ uint32_t slo[768];
  int t = threadIdx.x;
  int ib = blockIdx.x >> 3, c = blockIdx.x & 7, base = c * 768;
  for (int j = t; j < 768; j += 512) { shi[j] = keyhi[base + j]; slo[j] = keylo[base + j]; }
  __syncthreads();
  int i = ib * 256 + (t >> 1);
  int h = t & 1;
  uint64_t hi = keyhi[i]; uint32_t lo = keylo[i];
  uint32_t cnt = 0;
  int j0 = h * 384;
  for (int j = j0; j < j0 + 384; ++j) {
    uint64_t hj = shi[j]; uint32_t lj = slo[j];
    cnt += ((hj > hi) || (hj == hi && lj > lo)) ? 1u : 0u;
  }
  rank2d[i * 16 + c * 2 + h] = cnt;
}

// ---------- seq body: single-wave batched-greedy NMS (barrier-free) ----------
#define FOR16(F) F(0) F(1) F(2) F(3) F(4) F(5) F(6) F(7) \
                 F(8) F(9) F(10) F(11) F(12) F(13) F(14) F(15)

static __device__ void seq_body(const unsigned long long* __restrict__ valid,
    const uint64_t* __restrict__ M, const float4* __restrict__ sobox,
    float* __restrict__ out, int* __restrict__ cslot) {
  int l = threadIdx.x;                          // < 64 (caller-guaranteed)
  unsigned long long v0 = valid[l];
  unsigned long long v1 = (l < 32) ? valid[64 + l] : 0ull;
  uint32_t cnt = 0;

  for (;;) {
    uint32_t n0 = (uint32_t)__popcll(v0);
    uint32_t inc0 = wscan(n0, l);
    uint32_t T0 = __shfl(inc0, 63);
    uint32_t ex0 = inc0 - n0;
    uint32_t n1 = (uint32_t)__popcll(v1);
    uint32_t inc1 = wscan(n1, l);
    uint32_t T1 = __shfl(inc1, 63);
    uint32_t ex1 = T0 + inc1 - n1;
    uint32_t TV = T0 + T1;
    if (cnt >= POST_NMS_ || TV == 0) break;
    uint32_t m = (TV < KB) ? TV : KB;

    if (l < KB) cslot[l] = 0;
    __builtin_amdgcn_sched_barrier(0);
    if (ex0 < KB) {
      unsigned long long w = v0; uint32_t r = ex0;
      while (w && r < KB) { int b = __ffsll(w) - 1; cslot[r] = l * 64 + b; ++r; w &= w - 1; }
    }
    if (ex1 < KB && v1) {
      unsigned long long w = v1; uint32_t r = ex1;
      while (w && r < KB) { int b = __ffsll(w) - 1; cslot[r] = (64 + l) * 64 + b; ++r; w &= w - 1; }
    }
    __builtin_amdgcn_sched_barrier(0);

#define ROWDECL(k) uint64_t rm0_##k = 0, rm1_##k = 0;
    FOR16(ROWDECL)
#undef ROWDECL
#define ROWLOAD(k) if (k < (int)m) { const uint64_t* p = M + (size_t)cslot[k] * NWORD; \
                     rm0_##k = p[l]; rm1_##k = (l < 32) ? p[64 + l] : 0ull; }
    FOR16(ROWLOAD)
#undef ROWLOAD
    float4 obox = make_float4(0.f, 0.f, 0.f, 0.f);
    if (l < KB) obox = sobox[cslot[l]];

    uint32_t cj = (l < KB) ? (uint32_t)cslot[l] : 0u;
    uint32_t wj = cj >> 6, bj = cj & 63;
    int srcA = (int)(wj & 63), srcB = (int)(wj & 31);
    uint32_t srow[KB];
#define SROW(k) { uint64_t a = __shfl((unsigned long long)rm0_##k, srcA); \
                  uint64_t b = __shfl((unsigned long long)rm1_##k, srcB); \
                  uint64_t sel = (wj < 64) ? a : b; \
                  uint32_t bit = (l < KB && k < (int)m) ? (uint32_t)((sel >> bj) & 1) : 0u; \
                  srow[k] = (uint32_t)(__ballot(bit) & 0xFFFFull); }
    FOR16(SROW)
#undef SROW

    uint32_t cnt0 = cnt;
    uint32_t wm = 0, supp = 0;
    #pragma unroll
    for (int k = 0; k < KB; ++k) {
      if (k < (int)m && cnt < POST_NMS_ && !((supp >> k) & 1)) {
        wm |= 1u << k; ++cnt; supp |= srow[k];
      }
    }

    if (l < KB && ((wm >> l) & 1)) {
      uint32_t pos = cnt0 + (uint32_t)__popc(wm & ((1u << l) - 1));
      *(float4*)(out + (size_t)pos * 4) = obox;
    }

    uint64_t comb0 = 0, comb1 = 0;
#define COMB(k) if ((wm >> k) & 1) { comb0 |= rm0_##k; comb1 |= rm1_##k; }
    FOR16(COMB)
#undef COMB
    v0 &= ~comb0; v1 &= ~comb1;
  }

  for (int j = l; j < (int)(POST_NMS_ - cnt) * 4; j += 64) out[cnt * 4 + j] = 0.0f;
}

// ---------- K6: scatter+mat fused; LAST block runs seq ----------
__global__ __launch_bounds__(512) void k_matsc(const uint64_t* __restrict__ keyhi,
                                               const uint32_t* __restrict__ rank2d,
                                               const float4* __restrict__ box4u,
                                               float4* __restrict__ sobox,
                                               unsigned long long* __restrict__ valid,
                                               uint64_t* __restrict__ M,
                                               uint32_t* __restrict__ ctr,
                                               float* __restrict__ out) {
  __shared__ float4 sb[NPAD];       // 98,304 B
  __shared__ float  sa[NPAD];       // 24,576 B
  __shared__ int    cslot[KB];
  __shared__ uint32_t lastf;
  int t = threadIdx.x;
  int b = blockIdx.x;
  for (int i = t; i < NPAD; i += 512) {
    const uint4* rp = (const uint4*)(rank2d + (size_t)i * 16);
    uint4 r0 = rp[0], r1 = rp[1], r2 = rp[2], r3 = rp[3];
    uint32_t r = r0.x+r0.y+r0.z+r0.w + r1.x+r1.y+r1.z+r1.w
               + r2.x+r2.y+r2.z+r2.w + r3.x+r3.y+r3.z+r3.w;
    float4 bx = box4u[i];
    float x2 = bx.x + bx.z - 1.0f;              // exactly as reference _nms
    float y2 = bx.y + bx.w - 1.0f;
    sb[r] = make_float4(bx.x, bx.y, x2, y2);
    sa[r] = bx.z * bx.w;
    if (b == 0) {
      sobox[r] = bx;
      uint32_t d = ~(uint32_t)(keyhi[i] & 0xFFFFFFFFu);
      if (d < 0xFF800000u)                      // finite masked score only
        atomicOr(&valid[r >> 6], 1ull << (r & 63));
    }
  }
  __syncthreads();
  int wid = t >> 6, l = t & 63;
  #pragma unroll
  for (int rr = 0; rr < 4; ++rr) {
    int r = b * 32 + wid * 4 + rr;
    float4 rb = sb[r];
    for (int w = 0; w < NWORD; ++w) {
      int j = w * 64 + l;
      float4 cb = sb[j];
      float ca = sa[j];
      float xx1 = fmaxf(cb.x, rb.x), yy1 = fmaxf(cb.y, rb.y);
      float xx2 = fminf(cb.z, rb.z), yy2 = fminf(cb.w, rb.w);
      float iw = fmaxf(xx2 - xx1 + 1.0f, 0.0f);
      float ih = fmaxf(yy2 - yy1 + 1.0f, 0.0f);
      float ratio = (iw * ih) / ca;             // IEEE divide, exact semantics
      unsigned long long mm = __ballot(!(ratio < 0.7f));
      if (l == 0) M[(size_t)r * NWORD + w] = mm;
    }
  }
  // ---- last-block-runs-seq (release/acquire via device fence + atomic) ----
  __syncthreads();
  __threadfence();                              // release this block's M (+sobox/valid)
  if (t == 0) lastf = (atomicAdd(&ctr[8], 1u) == (uint32_t)(gridDim.x - 1)) ? 1u : 0u;
  __syncthreads();
  if (lastf) {
    __threadfence();                            // acquire: invalidate stale L2 lines
    if (t < 64) seq_body(valid, M, sobox, out, cslot);
  }
}

// ---------- launch ----------
extern "C" void kernel_launch(void* const* d_in, const int* in_sizes, int n_in,
                              void* d_out, int out_size, void* d_ws, size_t ws_size,
                              hipStream_t stream) {
  const float*  scores  = (const float*)d_in[0];
  const float4* deltas  = (const float4*)d_in[1];
  const float4* anchors = (const float4*)d_in[2];
  float* out = (float*)d_out;

  uint8_t* w8 = (uint8_t*)d_ws;
  // region 0: d[] (5,308,416 B), live hA..gather; then overlaid by M + sobox
  uint32_t* darr  = (uint32_t*)w8;
  uint64_t* M     = (uint64_t*)w8;                          // 4,718,592
  float4*   sobox = (float4*)(w8 + 4841472);                //  98,304 -> 4,939,776
  // region 1 (fresh): @5,308,416
  uint64_t* keyhi  = (uint64_t*)(w8 + 5308416);             //  49,152
  uint32_t* keylo  = (uint32_t*)(w8 + 5357568);             //  24,576
  float4*   box4u  = (float4*)  (w8 + 5382144);             //  98,304
  uint32_t* rank2d = (uint32_t*)(w8 + 5480448);             // 393,216 -> 5,873,664
  // region 2: persistent small; hist2+ctr+valid contiguous (zeroed by hA block 0)
  uint32_t* hist1 = (uint32_t*)(w8 + 5873664);              //   1,280 (320 u32)
  uint32_t* hist2 = (uint32_t*)(w8 + 5874944);              //   4,096
  uint32_t* ctr   = (uint32_t*)(w8 + 5879040);              //      64
  unsigned long long* valid = (unsigned long long*)(w8 + 5879104); // 1,024
  uint64_t* L    = (uint64_t*)(w8 + 5880128);               //  48,000
  uint64_t* Lb   = (uint64_t*)(w8 + 5928128);               //  32,768 -> 5,960,896 total

  const uint4* dv = (const uint4*)darr;

  hipMemsetAsync(hist1, 0, 1280, stream);      // hist1 only; hist2/ctr/valid zeroed in k_hA

  k_hA    <<<NB, 256, 0, stream>>>(scores, deltas, anchors, darr, hist1, hist2);
  k_hB    <<<NB, 256, 0, stream>>>(dv, hist1, hist2);
  k_gather<<<NB, 256, 0, stream>>>(dv, hist1, hist2, ctr, L, Lb);
  k_prep  <<<NPAD / 256, 256, 0, stream>>>(hist1, hist2, ctr, L, Lb, deltas, anchors,
                                           keyhi, keylo, box4u);
  k_rank  <<<MATB, 512, 0, stream>>>(keyhi, keylo, rank2d);
  k_matsc <<<MATB, 512, 0, stream>>>(keyhi, rank2d, box4u, sobox, valid, M, ctr, out);
}